// Round 12
// baseline (217.718 us; speedup 1.0000x reference)
//
#include <hip/hip_runtime.h>
#include <math.h>

#define NB 4
#define NP 4096   // src points per batch
#define MP 4096   // tgt points per batch

typedef __bf16 bf16x8 __attribute__((ext_vector_type(8)));
typedef float  f32x16 __attribute__((ext_vector_type(16)));

// round-to-nearest-even fp32 -> bf16 (as raw u16)
static __device__ __forceinline__ unsigned short bh(float f) {
    unsigned u = __float_as_uint(f);
    unsigned r = (u + 0x7FFFu + ((u >> 16) & 1u)) >> 16;
    return (unsigned short)r;
}
static __device__ __forceinline__ float hf(unsigned short h) {
    return __uint_as_float(((unsigned)h) << 16);
}

// ---------------------------------------------------------------------------
// fp32 3x3 Kabsch from the 15 reduced sums. Fixed 5 Jacobi sweeps.
// RtL: R row-major [0..8], t [9..11]; transform is p' = p @ R + t.
// ---------------------------------------------------------------------------
__device__ __forceinline__ void kabsch_f32(const float* s, float* RtL) {
    const float invN = 1.0f / (float)NP;
    float cs[3] = { s[0] * invN, s[1] * invN, s[2] * invN };
    float ct[3] = { s[3] * invN, s[4] * invN, s[5] * invN };
    float H[3][3];
    for (int d = 0; d < 3; ++d)
        for (int e = 0; e < 3; ++e)
            H[d][e] = s[6 + d * 3 + e] * invN - cs[d] * ct[e];

    float A[3][3];
    for (int i = 0; i < 3; ++i)
        for (int j = 0; j < 3; ++j)
            A[i][j] = H[0][i] * H[0][j] + H[1][i] * H[1][j] + H[2][i] * H[2][j];

    float V[3][3] = {{1, 0, 0}, {0, 1, 0}, {0, 0, 1}};
    for (int sweep = 0; sweep < 5; ++sweep) {
        for (int pi = 0; pi < 3; ++pi) {
            const int p = (pi == 2) ? 1 : 0;
            const int q = (pi == 0) ? 1 : 2;
            float apq = A[p][q];
            if (fabsf(apq) < 1e-30f) continue;
            float theta = (A[q][q] - A[p][p]) / (2.0f * apq);
            float t = 1.0f / (fabsf(theta) + sqrtf(1.0f + theta * theta));
            if (theta < 0.0f) t = -t;
            float cth = 1.0f / sqrtf(1.0f + t * t);
            float sth = t * cth;
            float App = A[p][p], Aqq = A[q][q];
            A[p][p] = App - t * apq;
            A[q][q] = Aqq + t * apq;
            A[p][q] = A[q][p] = 0.0f;
            const int r = 3 - p - q;
            float Apr = A[p][r], Aqr = A[q][r];
            A[p][r] = A[r][p] = cth * Apr - sth * Aqr;
            A[q][r] = A[r][q] = sth * Apr + cth * Aqr;
            for (int i = 0; i < 3; ++i) {
                float Vip = V[i][p], Viq = V[i][q];
                V[i][p] = cth * Vip - sth * Viq;
                V[i][q] = sth * Vip + cth * Viq;
            }
        }
    }
    float lam[3] = { A[0][0], A[1][1], A[2][2] };
    for (int i = 0; i < 2; ++i)
        for (int j = i + 1; j < 3; ++j)
            if (lam[j] > lam[i]) {
                float tl = lam[i]; lam[i] = lam[j]; lam[j] = tl;
                for (int k = 0; k < 3; ++k) {
                    float tv = V[k][i]; V[k][i] = V[k][j]; V[k][j] = tv;
                }
            }

    float U[3][3];
    for (int k = 0; k < 3; ++k) {
        float w0 = H[0][0] * V[0][k] + H[0][1] * V[1][k] + H[0][2] * V[2][k];
        float w1 = H[1][0] * V[0][k] + H[1][1] * V[1][k] + H[1][2] * V[2][k];
        float w2 = H[2][0] * V[0][k] + H[2][1] * V[1][k] + H[2][2] * V[2][k];
        float nrm = sqrtf(w0 * w0 + w1 * w1 + w2 * w2);
        if (nrm > 1e-20f) {
            U[0][k] = w0 / nrm; U[1][k] = w1 / nrm; U[2][k] = w2 / nrm;
        } else {
            U[0][k] = U[1][0] * U[2][1] - U[2][0] * U[1][1];
            U[1][k] = U[2][0] * U[0][1] - U[0][0] * U[2][1];
            U[2][k] = U[0][0] * U[1][1] - U[1][0] * U[0][1];
        }
    }

    float detH = H[0][0] * (H[1][1] * H[2][2] - H[1][2] * H[2][1])
               - H[0][1] * (H[1][0] * H[2][2] - H[1][2] * H[2][0])
               + H[0][2] * (H[1][0] * H[2][1] - H[1][1] * H[2][0]);
    float sgn = (detH < 0.0f) ? -1.0f : 1.0f;

    float R[3][3];
    for (int i = 0; i < 3; ++i)
        for (int j = 0; j < 3; ++j)
            R[i][j] = V[i][0] * U[j][0] + V[i][1] * U[j][1] + sgn * V[i][2] * U[j][2];
    float tv[3];
    for (int i = 0; i < 3; ++i)
        tv[i] = ct[i] - (R[i][0] * cs[0] + R[i][1] * cs[1] + R[i][2] * cs[2]);

    for (int i = 0; i < 3; ++i)
        for (int j = 0; j < 3; ++j)
            RtL[i * 3 + j] = R[i][j];
    for (int i = 0; i < 3; ++i) RtL[9 + i] = tv[i];
}

// Reduce the 128 partial rows of batch b (lane l reads rows b*128+l and
// b*128+64+l), solve step S, compose with RcIn -> McL (and optionally StL).
// Deterministic & identical in every calling block.
__device__ __forceinline__ void solve_compose128(const float* __restrict__ pprev,
                                                 const float* __restrict__ RcIn,
                                                 int b, int l,
                                                 float* __restrict__ McL,
                                                 float* __restrict__ StL) {
    const float4* rp0 = (const float4*)(pprev + (b * 128 + l) * 16);
    const float4* rp1 = (const float4*)(pprev + (b * 128 + 64 + l) * 16);
    float4 a0 = rp0[0], a1 = rp0[1], a2 = rp0[2], a3 = rp0[3];
    float4 c0 = rp1[0], c1 = rp1[1], c2 = rp1[2], c3 = rp1[3];
    float sm[15] = { a0.x + c0.x, a0.y + c0.y, a0.z + c0.z, a0.w + c0.w,
                     a1.x + c1.x, a1.y + c1.y, a1.z + c1.z, a1.w + c1.w,
                     a2.x + c2.x, a2.y + c2.y, a2.z + c2.z, a2.w + c2.w,
                     a3.x + c3.x, a3.y + c3.y, a3.z + c3.z };
    #pragma unroll
    for (int k = 0; k < 15; ++k) {
        float v = sm[k];
        v += __shfl_down(v, 32);
        v += __shfl_down(v, 16);
        v += __shfl_down(v, 8);
        v += __shfl_down(v, 4);
        v += __shfl_down(v, 2);
        v += __shfl_down(v, 1);
        sm[k] = v;
    }
    if (l == 0) {
        float St[12];
        kabsch_f32(sm, St);
        const float* mc = RcIn + b * 12;
        float Mo[12];
        for (int i = 0; i < 3; ++i)
            for (int j = 0; j < 3; ++j)
                Mo[i * 3 + j] = mc[i * 3 + 0] * St[j] +
                                mc[i * 3 + 1] * St[3 + j] +
                                mc[i * 3 + 2] * St[6 + j];
        for (int j = 0; j < 3; ++j)
            Mo[9 + j] = mc[9] * St[j] + mc[10] * St[3 + j] +
                        mc[11] * St[6 + j] + St[9 + j];
        #pragma unroll
        for (int i = 0; i < 12; ++i) McL[i] = Mo[i];
        if (StL) {
            #pragma unroll
            for (int i = 0; i < 12; ++i) StL[i] = St[i];
        }
    }
}

// ---------------------------------------------------------------------------
// Init: tgt4 (x,y,z,|t|^2) and pre-packed bf16 hi/lo B-fragments (R8 layout,
// HW-verified). Bbuf: [b][tile(128)][lane(64)] uint4.
// ---------------------------------------------------------------------------
__global__ __launch_bounds__(256) void icp_init(const float* __restrict__ tgt,
                                                float4* __restrict__ tgt4,
                                                uint4* __restrict__ Bbuf) {
    const int t    = blockIdx.x * 256 + threadIdx.x;   // 0..32767
    const int b    = t >> 13;
    const int rem  = t & 8191;
    const int tile = rem >> 6;
    const int lane = rem & 63;
    const int n    = lane & 31;
    const int h    = lane >> 5;
    const int gt   = b * MP + tile * 32 + n;

    float x = tgt[gt * 3 + 0];
    float y = tgt[gt * 3 + 1];
    float z = tgt[gt * 3 + 2];
    float wv = x * x + y * y + z * z;

    unsigned short xh = bh(x), xl = bh(x - hf(xh));
    unsigned short yh = bh(y), yl = bh(y - hf(yh));
    unsigned short zh = bh(z), zl = bh(z - hf(zh));
    unsigned short wh = bh(wv), wl = bh(wv - hf(wh));
    const unsigned short ONE = 0x3F80;

    unsigned short s0, s1, s2, s3, s4, s5, s6, s7;
    if (h == 0) { s0 = xh; s1 = xh; s2 = xl; s3 = xl;
                  s4 = yh; s5 = yh; s6 = yl; s7 = yl; }
    else        { s0 = zh; s1 = zh; s2 = zl; s3 = zl;
                  s4 = wh; s5 = wl; s6 = ONE; s7 = ONE; }
    uint4 u;
    u.x = (unsigned)s0 | ((unsigned)s1 << 16);
    u.y = (unsigned)s2 | ((unsigned)s3 << 16);
    u.z = (unsigned)s4 | ((unsigned)s5 << 16);
    u.w = (unsigned)s6 | ((unsigned)s7 << 16);
    Bbuf[t] = u;
    if (h == 0) tgt4[gt] = make_float4(x, y, z, wv);
}

// ---------------------------------------------------------------------------
// One ICP iteration per dispatch. 512 blocks (batch b = blk>>7, src-group
// g = blk&127 of 32 points; lane owns src m = l&31), 512 threads = 8 waves
// -> 2 blocks/CU so one block's MFMA work hides the other's serial wave-0
// prologue (the mechanism this round tests). Wave w scans tgt tiles
// [w*16, w*16+16) with the R8 register rotation (fb[4], hoisted before the
// prologue). Composition transform (no S round-trip); Rc written
// redundantly (benign identical race, proven R10/R11). R8-style wave-0
// tail with sel masking (lanes 32-63 are duplicates).
// ---------------------------------------------------------------------------
__global__ __launch_bounds__(512, 4) void icp_scan(
        const float* __restrict__ src,
        const float4* __restrict__ tgt4,
        const uint4* __restrict__ Bbuf,
        const float* __restrict__ pprev,  // [512][16] prev partials
        float* __restrict__ pout,         // [512][16] this iter's partials
        const float* __restrict__ RcIn,   // [NB][12] composed (prev)
        float* __restrict__ RcOut,        // [NB][12] composed (this)
        int first) {
    __shared__ unsigned CK[256];          // [wave(8)][src-row(32)]
    __shared__ float McL[12];

    const int blk = blockIdx.x;
    const int b   = blk >> 7;
    const int g   = blk & 127;
    const int tid = threadIdx.x;
    const int w   = tid >> 6;
    const int l   = tid & 63;
    const int m   = l & 31;
    const int h   = l >> 5;

    // ---- hoist src point + first 4 B-tiles (fly during the prologue) ----
    const int gsrc = b * NP + g * 32 + m;
    const float x0 = src[gsrc * 3 + 0];
    const float y0 = src[gsrc * 3 + 1];
    const float z0 = src[gsrc * 3 + 2];
    const uint4* Bw = Bbuf + (b * 128 + w * 16) * 64;
    uint4 fb[4];
    fb[0] = Bw[l];
    fb[1] = Bw[64 + l];
    fb[2] = Bw[128 + l];
    fb[3] = Bw[192 + l];

    // ---- prologue: wave 0 solves prev step, composes, publishes ----
    if (w == 0) {
        if (first) {
            if (l == 0) {
                #pragma unroll
                for (int i = 0; i < 12; ++i) {
                    float v = (i == 0 || i == 4 || i == 8) ? 1.0f : 0.0f;
                    McL[i] = v;
                    RcOut[b * 12 + i] = v;
                }
            }
        } else {
            solve_compose128(pprev, RcIn, b, l, McL, nullptr);
            if (l == 0) {
                #pragma unroll
                for (int i = 0; i < 12; ++i) RcOut[b * 12 + i] = McL[i];
            }
        }
    }
    __syncthreads();

    // ---- apply composed transform to the ORIGINAL src point ----
    const float px = x0 * McL[0] + y0 * McL[3] + z0 * McL[6] + McL[9];
    const float py = x0 * McL[1] + y0 * McL[4] + z0 * McL[7] + McL[10];
    const float pz = x0 * McL[2] + y0 * McL[5] + z0 * McL[8] + McL[11];

    // ---- A-fragment: A[m=lane&31][k=(lane>>5)*8+j] (own point, no shfl) ----
    union { unsigned short s[8]; bf16x8 v; } Af;
    {
        float ax = -2.0f * px, ay = -2.0f * py, az = -2.0f * pz;
        float qv = px * px + py * py + pz * pz + 1.0f;
        unsigned short axh = bh(ax), axl = bh(ax - hf(axh));
        unsigned short ayh = bh(ay), ayl = bh(ay - hf(ayh));
        unsigned short azh = bh(az), azl = bh(az - hf(azh));
        unsigned short qh  = bh(qv), ql  = bh(qv - hf(qh));
        const unsigned short ONE = 0x3F80;
        if (h == 0) {
            Af.s[0] = axh; Af.s[1] = axl; Af.s[2] = axh; Af.s[3] = axl;
            Af.s[4] = ayh; Af.s[5] = ayl; Af.s[6] = ayh; Af.s[7] = ayl;
        } else {
            Af.s[0] = azh; Af.s[1] = azl; Af.s[2] = azh; Af.s[3] = azl;
            Af.s[4] = ONE; Af.s[5] = ONE; Af.s[6] = qh;  Af.s[7] = ql;
        }
    }

    // ---- 16-tile MFMA scan, R8 register rotation + epilogue ----
    f32x16 zero;
    #pragma unroll
    for (int i = 0; i < 16; ++i) zero[i] = 0.0f;
    float best[16];
    #pragma unroll
    for (int r = 0; r < 16; ++r) best[r] = __uint_as_float(0x7F7FFFFFu);

    const int col = m;
    #pragma unroll
    for (int t = 0; t < 16; ++t) {
        bf16x8 Bf = __builtin_bit_cast(bf16x8, fb[t & 3]);
        if (t < 12) fb[t & 3] = Bw[(t + 4) * 64 + l];
        f32x16 d16 = __builtin_amdgcn_mfma_f32_32x32x16_bf16(Af.v, Bf, zero,
                                                             0, 0, 0);
        const unsigned idxk = (unsigned)((w * 16 + t) * 32 + col);
        #pragma unroll
        for (int r = 0; r < 16; r += 2) {
            float k0 = __uint_as_float(
                (__float_as_uint(d16[r]) & 0xFFFFF000u) | idxk);
            float k1 = __uint_as_float(
                (__float_as_uint(d16[r + 1]) & 0xFFFFF000u) | idxk);
            best[r]     = fminf(best[r], k0);
            best[r + 1] = fminf(best[r + 1], k1);
        }
    }

    // ---- reduce across the 32 columns ----
    #pragma unroll
    for (int r = 0; r < 16; ++r) {
        float v = best[r];
        v = fminf(v, __shfl_xor(v, 1));
        v = fminf(v, __shfl_xor(v, 2));
        v = fminf(v, __shfl_xor(v, 4));
        v = fminf(v, __shfl_xor(v, 8));
        v = fminf(v, __shfl_xor(v, 16));
        best[r] = v;
    }
    if (col == 0) {
        #pragma unroll
        for (int r = 0; r < 16; ++r) {
            const int row = (r & 3) + 8 * (r >> 2) + 4 * h;
            CK[w * 32 + row] = __float_as_uint(best[r]);
        }
    }
    __syncthreads();

    // ---- wave 0 tail: combine 8 ranges, gather match, masked 15-sum ----
    if (w == 0) {
        unsigned kb = CK[m];
        #pragma unroll
        for (int k = 1; k < 8; ++k) {
            unsigned kk = CK[k * 32 + m];
            kb = kk < kb ? kk : kb;
        }
        float4 mt = tgt4[b * MP + (kb & 0xFFF)];
        const float sel = (l < 32) ? 1.0f : 0.0f;
        const float sx = px * sel, sy = py * sel, sz = pz * sel;
        const float tx = mt.x * sel, ty = mt.y * sel, tz = mt.z * sel;

        float v[15];
        v[0]  = sx;      v[1]  = sy;      v[2]  = sz;
        v[3]  = tx;      v[4]  = ty;      v[5]  = tz;
        v[6]  = sx * tx; v[7]  = sx * ty; v[8]  = sx * tz;
        v[9]  = sy * tx; v[10] = sy * ty; v[11] = sy * tz;
        v[12] = sz * tx; v[13] = sz * ty; v[14] = sz * tz;
        #pragma unroll
        for (int k = 0; k < 15; ++k) {
            float s = v[k];
            s += __shfl_down(s, 32);
            s += __shfl_down(s, 16);
            s += __shfl_down(s, 8);
            s += __shfl_down(s, 4);
            s += __shfl_down(s, 2);
            s += __shfl_down(s, 1);
            v[k] = s;
        }
        if (l == 0) {
            float* pp = pout + blk * 16;
            #pragma unroll
            for (int k = 0; k < 15; ++k) pp[k] = v[k];
        }
    }
}

// Final: every block redundantly solves iteration-10's step from P_9,
// composes with Mc_9, applies to original src, writes all outputs.
// out layout: R [4,3,3] flat (36), t [4,3] flat (12), points [4,4096,3].
__global__ __launch_bounds__(256) void icp_final(
        const float* __restrict__ src,
        const float* __restrict__ plast,  // [512][16]
        const float* __restrict__ RcIn,   // [NB][12] = Mc_9
        float* __restrict__ out) {
    __shared__ float McL[12];
    __shared__ float StL[12];
    const int bk  = blockIdx.x;
    const int tid = threadIdx.x;
    const int gid = bk * 256 + tid;               // 0..16383
    const int b   = gid >> 12;

    if (tid < 64) solve_compose128(plast, RcIn, b, tid, McL, StL);
    __syncthreads();

    float x = src[gid * 3 + 0];
    float y = src[gid * 3 + 1];
    float z = src[gid * 3 + 2];
    out[48 + gid * 3 + 0] = x * McL[0] + y * McL[3] + z * McL[6] + McL[9];
    out[48 + gid * 3 + 1] = x * McL[1] + y * McL[4] + z * McL[7] + McL[10];
    out[48 + gid * 3 + 2] = x * McL[2] + y * McL[5] + z * McL[8] + McL[11];
    if ((bk & 15) == 0) {
        if (tid < 9) out[b * 9 + tid] = StL[tid];
        if (tid < 3) out[36 + b * 3 + tid] = StL[9 + tid];
    }
}

extern "C" void kernel_launch(void* const* d_in, const int* in_sizes, int n_in,
                              void* d_out, int out_size, void* d_ws, size_t ws_size,
                              hipStream_t stream) {
    const float* src = (const float*)d_in[0];
    const float* tgt = (const float*)d_in[1];
    float* out = (float*)d_out;

    float* W     = (float*)d_ws;
    float4* tgt4 = (float4*)W;                     // 65536 floats
    uint4*  Bbuf = (uint4*)(W + 65536);            // 131072 floats (512 KB)
    float*  P0   = W + 65536 + 131072;             // 512*16
    float*  P1   = P0 + 8192;                      // 512*16
    float*  Rc0  = P1 + 8192;                      // 4*12
    float*  Rc1  = Rc0 + 48;                       // 4*12
    float* P[2]  = { P0, P1 };
    float* Rc[2] = { Rc0, Rc1 };

    icp_init<<<128, 256, 0, stream>>>(tgt, tgt4, Bbuf);
    for (int k = 0; k < 10; ++k) {
        icp_scan<<<512, 512, 0, stream>>>(src, tgt4, Bbuf,
                                          P[(k + 1) & 1], P[k & 1],
                                          Rc[(k + 1) & 1], Rc[k & 1],
                                          k == 0 ? 1 : 0);
    }
    icp_final<<<64, 256, 0, stream>>>(src, P[1], Rc[1], out);
}

// Round 14
// 192.893 us; speedup vs baseline: 1.1287x; 1.1287x over previous
//
#include <hip/hip_runtime.h>
#include <math.h>

#define NB 4
#define NP 4096   // src points per batch
#define MP 4096   // tgt points per batch

typedef __bf16 bf16x8 __attribute__((ext_vector_type(8)));
typedef float  f32x16 __attribute__((ext_vector_type(16)));

// round-to-nearest-even fp32 -> bf16 (as raw u16)
static __device__ __forceinline__ unsigned short bh(float f) {
    unsigned u = __float_as_uint(f);
    unsigned r = (u + 0x7FFFu + ((u >> 16) & 1u)) >> 16;
    return (unsigned short)r;
}
static __device__ __forceinline__ float hf(unsigned short h) {
    return __uint_as_float(((unsigned)h) << 16);
}

// ---------------------------------------------------------------------------
// fp32 3x3 Kabsch from the 15 reduced sums (identical to R4-R6).
// ---------------------------------------------------------------------------
__device__ __forceinline__ void kabsch_f32(const float* s, float* RtL) {
    const float invN = 1.0f / (float)NP;
    float cs[3] = { s[0] * invN, s[1] * invN, s[2] * invN };
    float ct[3] = { s[3] * invN, s[4] * invN, s[5] * invN };
    float H[3][3];
    for (int d = 0; d < 3; ++d)
        for (int e = 0; e < 3; ++e)
            H[d][e] = s[6 + d * 3 + e] * invN - cs[d] * ct[e];

    float A[3][3];
    for (int i = 0; i < 3; ++i)
        for (int j = 0; j < 3; ++j)
            A[i][j] = H[0][i] * H[0][j] + H[1][i] * H[1][j] + H[2][i] * H[2][j];

    float V[3][3] = {{1, 0, 0}, {0, 1, 0}, {0, 0, 1}};
    for (int sweep = 0; sweep < 8; ++sweep) {
        float off = A[0][1] * A[0][1] + A[0][2] * A[0][2] + A[1][2] * A[1][2];
        if (off < 1e-16f) break;
        for (int pi = 0; pi < 3; ++pi) {
            const int p = (pi == 2) ? 1 : 0;
            const int q = (pi == 0) ? 1 : 2;
            float apq = A[p][q];
            if (fabsf(apq) < 1e-30f) continue;
            float theta = (A[q][q] - A[p][p]) / (2.0f * apq);
            float t = 1.0f / (fabsf(theta) + sqrtf(1.0f + theta * theta));
            if (theta < 0.0f) t = -t;
            float cth = 1.0f / sqrtf(1.0f + t * t);
            float sth = t * cth;
            float App = A[p][p], Aqq = A[q][q];
            A[p][p] = App - t * apq;
            A[q][q] = Aqq + t * apq;
            A[p][q] = A[q][p] = 0.0f;
            const int r = 3 - p - q;
            float Apr = A[p][r], Aqr = A[q][r];
            A[p][r] = A[r][p] = cth * Apr - sth * Aqr;
            A[q][r] = A[r][q] = sth * Apr + cth * Aqr;
            for (int i = 0; i < 3; ++i) {
                float Vip = V[i][p], Viq = V[i][q];
                V[i][p] = cth * Vip - sth * Viq;
                V[i][q] = sth * Vip + cth * Viq;
            }
        }
    }
    float lam[3] = { A[0][0], A[1][1], A[2][2] };
    for (int i = 0; i < 2; ++i)
        for (int j = i + 1; j < 3; ++j)
            if (lam[j] > lam[i]) {
                float tl = lam[i]; lam[i] = lam[j]; lam[j] = tl;
                for (int k = 0; k < 3; ++k) {
                    float tv = V[k][i]; V[k][i] = V[k][j]; V[k][j] = tv;
                }
            }

    float U[3][3];
    for (int k = 0; k < 3; ++k) {
        float w0 = H[0][0] * V[0][k] + H[0][1] * V[1][k] + H[0][2] * V[2][k];
        float w1 = H[1][0] * V[0][k] + H[1][1] * V[1][k] + H[1][2] * V[2][k];
        float w2 = H[2][0] * V[0][k] + H[2][1] * V[1][k] + H[2][2] * V[2][k];
        float nrm = sqrtf(w0 * w0 + w1 * w1 + w2 * w2);
        if (nrm > 1e-20f) {
            U[0][k] = w0 / nrm; U[1][k] = w1 / nrm; U[2][k] = w2 / nrm;
        } else {
            U[0][k] = U[1][0] * U[2][1] - U[2][0] * U[1][1];
            U[1][k] = U[2][0] * U[0][1] - U[0][0] * U[2][1];
            U[2][k] = U[0][0] * U[1][1] - U[1][0] * U[0][1];
        }
    }

    float detH = H[0][0] * (H[1][1] * H[2][2] - H[1][2] * H[2][1])
               - H[0][1] * (H[1][0] * H[2][2] - H[1][2] * H[2][0])
               + H[0][2] * (H[1][0] * H[2][1] - H[1][1] * H[2][0]);
    float sgn = (detH < 0.0f) ? -1.0f : 1.0f;

    float R[3][3];
    for (int i = 0; i < 3; ++i)
        for (int j = 0; j < 3; ++j)
            R[i][j] = V[i][0] * U[j][0] + V[i][1] * U[j][1] + sgn * V[i][2] * U[j][2];
    float tv[3];
    for (int i = 0; i < 3; ++i)
        tv[i] = ct[i] - (R[i][0] * cs[0] + R[i][1] * cs[1] + R[i][2] * cs[2]);

    for (int i = 0; i < 3; ++i)
        for (int j = 0; j < 3; ++j)
            RtL[i * 3 + j] = R[i][j];
    for (int i = 0; i < 3; ++i) RtL[9 + i] = tv[i];
}

// ---------------------------------------------------------------------------
// Init: build tgt4 (x,y,z,|t|^2) for gathers AND the pre-packed bf16 hi/lo
// B-fragments for mfma_f32_32x32x16_bf16.
// K-slot semantics (A x B pairing):
//   k0..3  : (-2sx){h,l,h,l} x tx{h,h,l,l}   -> -2 sx*tx   (all cross terms)
//   k4..7  : same for y;  k8..11: same for z
//   k12,13 : 1 x |t|^2{h,l}                   -> +|t|^2
//   k14,15 : (|s|^2+1){h,l} x 1               -> +|s|^2+1  (positivity)
// B lane layout (HW-verified in R8): B[n=lane&31][k=(lane>>5)*8+j].
// Bbuf: [b][tile(128)][lane(64)] x uint4 (8 bf16 each) = 512 KB.
// ---------------------------------------------------------------------------
__global__ __launch_bounds__(256) void icp_init(const float* __restrict__ tgt,
                                                float4* __restrict__ tgt4,
                                                uint4* __restrict__ Bbuf) {
    const int t    = blockIdx.x * 256 + threadIdx.x;   // 0..32767
    const int b    = t >> 13;
    const int rem  = t & 8191;
    const int tile = rem >> 6;        // 0..127 (32 tgt pts each)
    const int lane = rem & 63;
    const int n    = lane & 31;
    const int h    = lane >> 5;
    const int gt   = b * MP + tile * 32 + n;

    float x = tgt[gt * 3 + 0];
    float y = tgt[gt * 3 + 1];
    float z = tgt[gt * 3 + 2];
    float wv = x * x + y * y + z * z;

    unsigned short xh = bh(x), xl = bh(x - hf(xh));
    unsigned short yh = bh(y), yl = bh(y - hf(yh));
    unsigned short zh = bh(z), zl = bh(z - hf(zh));
    unsigned short wh = bh(wv), wl = bh(wv - hf(wh));
    const unsigned short ONE = 0x3F80;

    unsigned short s0, s1, s2, s3, s4, s5, s6, s7;
    if (h == 0) { s0 = xh; s1 = xh; s2 = xl; s3 = xl;
                  s4 = yh; s5 = yh; s6 = yl; s7 = yl; }
    else        { s0 = zh; s1 = zh; s2 = zl; s3 = zl;
                  s4 = wh; s5 = wl; s6 = ONE; s7 = ONE; }
    uint4 u;
    u.x = (unsigned)s0 | ((unsigned)s1 << 16);
    u.y = (unsigned)s2 | ((unsigned)s3 << 16);
    u.z = (unsigned)s4 | ((unsigned)s5 << 16);
    u.w = (unsigned)s6 | ((unsigned)s7 << 16);
    Bbuf[t] = u;

    if (h == 0) tgt4[gt] = make_float4(x, y, z, wv);
}

// ---------------------------------------------------------------------------
// One ICP iteration per dispatch. 256 blocks (batch b = blk>>6, src-group
// g = blk&63; lane l owns src point l), 1024 threads = 16 waves.
// Wave w: src-tile ts = w&1 (32 src), tgt-range tr = w>>1 (16 tiles x 32 tgt).
// Per tile: 1 coalesced uint4 load (B-frag) + 1 mfma_32x32x16_bf16 giving
// 1024 distances d = |s-t|^2 + 1 (hi/lo split, err ~2^-16) + 16x(and_or+min)
// key epilogue. Cross-col shfl_xor reduce, CK combine, wave-0 15-sum.
// Prologue: wave 0 redundantly solves prev (R,t) (fp32 Kabsch).
// ---------------------------------------------------------------------------
__global__ __launch_bounds__(1024) void icp_scan(
        const float* __restrict__ src,
        const float4* __restrict__ tgt4,
        const uint4* __restrict__ Bbuf,
        float* __restrict__ S,            // [NB*NP*3] transformed points
        const float* __restrict__ pprev,  // [256][16] prev partials
        float* __restrict__ pout,         // [256][16] this iter's partials
        int first) {
    __shared__ unsigned CK[512];          // [tr(8)][src(64)]
    __shared__ float RtL[12];

    const int blk = blockIdx.x;
    const int b   = blk >> 6;
    const int g   = blk & 63;
    const int tid = threadIdx.x;
    const int w   = tid >> 6;
    const int l   = tid & 63;
    const int ts  = w & 1;
    const int tr  = w >> 1;
    const int gsrc = b * NP + g * 64 + l;

    // ---- prologue: wave 0 redundantly solves prev iteration's (R,t) ----
    if (w == 0) {
        if (first) {
            if (l < 12) RtL[l] = (l == 0 || l == 4 || l == 8) ? 1.0f : 0.0f;
        } else {
            const float4* rp = (const float4*)(pprev + (b * 64 + l) * 16);
            float4 r0 = rp[0], r1 = rp[1], r2 = rp[2], r3 = rp[3];
            float sm[15] = { r0.x, r0.y, r0.z, r0.w, r1.x, r1.y, r1.z, r1.w,
                             r2.x, r2.y, r2.z, r2.w, r3.x, r3.y, r3.z };
            #pragma unroll
            for (int k = 0; k < 15; ++k) {
                float v = sm[k];
                v += __shfl_down(v, 32);
                v += __shfl_down(v, 16);
                v += __shfl_down(v, 8);
                v += __shfl_down(v, 4);
                v += __shfl_down(v, 2);
                v += __shfl_down(v, 1);
                sm[k] = v;
            }
            if (l == 0) kabsch_f32(sm, RtL);
        }
    }
    __syncthreads();

    // ---- transform own point; wave 1 persists it for the next iteration ----
    float px, py, pz;
    {
        const float* P = first ? src : S;
        float x = P[gsrc * 3 + 0];
        float y = P[gsrc * 3 + 1];
        float z = P[gsrc * 3 + 2];
        px = x * RtL[0] + y * RtL[3] + z * RtL[6] + RtL[9];
        py = x * RtL[1] + y * RtL[4] + z * RtL[7] + RtL[10];
        pz = x * RtL[2] + y * RtL[5] + z * RtL[8] + RtL[11];
    }
    if (w == 1) {
        S[gsrc * 3 + 0] = px;
        S[gsrc * 3 + 1] = py;
        S[gsrc * 3 + 2] = pz;
    }

    // ---- build A-fragment: A[m=lane&31][k=(lane>>5)*8+j] ----
    const int h = l >> 5;
    union { unsigned short s[8]; bf16x8 v; } Af;
    {
        const int j3 = ts * 32 + (l & 31);     // src point this lane's m maps to
        float pxj = __shfl(px, j3);
        float pyj = __shfl(py, j3);
        float pzj = __shfl(pz, j3);
        float ax = -2.0f * pxj, ay = -2.0f * pyj, az = -2.0f * pzj;
        float qv = pxj * pxj + pyj * pyj + pzj * pzj + 1.0f;
        unsigned short axh = bh(ax), axl = bh(ax - hf(axh));
        unsigned short ayh = bh(ay), ayl = bh(ay - hf(ayh));
        unsigned short azh = bh(az), azl = bh(az - hf(azh));
        unsigned short qh  = bh(qv), ql  = bh(qv - hf(qh));
        const unsigned short ONE = 0x3F80;
        if (h == 0) {
            Af.s[0] = axh; Af.s[1] = axl; Af.s[2] = axh; Af.s[3] = axl;
            Af.s[4] = ayh; Af.s[5] = ayl; Af.s[6] = ayh; Af.s[7] = ayl;
        } else {
            Af.s[0] = azh; Af.s[1] = azl; Af.s[2] = azh; Af.s[3] = azl;
            Af.s[4] = ONE; Af.s[5] = ONE; Af.s[6] = qh;  Af.s[7] = ql;
        }
    }

    // ---- 16-tile scan on the MFMA pipe ----
    f32x16 zero;
    #pragma unroll
    for (int i = 0; i < 16; ++i) zero[i] = 0.0f;

    float best[16];
    #pragma unroll
    for (int r = 0; r < 16; ++r) best[r] = __uint_as_float(0x7F7FFFFFu);

    const uint4* Bw = Bbuf + (b * 128 + tr * 16) * 64;
    const int col = l & 31;

    uint4 fb[4];
    fb[0] = Bw[l];
    fb[1] = Bw[64 + l];
    fb[2] = Bw[128 + l];
    fb[3] = Bw[192 + l];

    #pragma unroll
    for (int t = 0; t < 16; ++t) {
        bf16x8 Bf = __builtin_bit_cast(bf16x8, fb[t & 3]);
        if (t < 12) fb[t & 3] = Bw[(t + 4) * 64 + l];
        f32x16 d16 = __builtin_amdgcn_mfma_f32_32x32x16_bf16(Af.v, Bf, zero,
                                                             0, 0, 0);
        const unsigned idxk = (unsigned)((tr * 16 + t) * 32 + col);
        #pragma unroll
        for (int r = 0; r < 16; ++r) {
            float key = __uint_as_float(
                (__float_as_uint(d16[r]) & 0xFFFFF000u) | idxk);
            best[r] = fminf(best[r], key);
        }
    }

    // ---- reduce across the 32 columns (lanes within each half-wave) ----
    #pragma unroll
    for (int r = 0; r < 16; ++r) {
        float v = best[r];
        v = fminf(v, __shfl_xor(v, 1));
        v = fminf(v, __shfl_xor(v, 2));
        v = fminf(v, __shfl_xor(v, 4));
        v = fminf(v, __shfl_xor(v, 8));
        v = fminf(v, __shfl_xor(v, 16));
        best[r] = v;
    }
    if ((l & 31) == 0) {
        #pragma unroll
        for (int r = 0; r < 16; ++r) {
            const int row = (r & 3) + 8 * (r >> 2) + 4 * h;
            CK[tr * 64 + ts * 32 + row] = __float_as_uint(best[r]);
        }
    }
    __syncthreads();

    // ---- wave 0: combine 8 tgt-ranges, gather match, 15-sum ----
    if (w == 0) {
        unsigned kb = CK[l];
        #pragma unroll
        for (int k = 1; k < 8; ++k) {
            unsigned kk = CK[k * 64 + l];
            kb = kk < kb ? kk : kb;
        }
        const int idx = kb & 0xFFF;
        float4 mt = tgt4[b * MP + idx];
        const float tx = mt.x, ty = mt.y, tz = mt.z;

        float v[15];
        v[0]  = px;      v[1]  = py;      v[2]  = pz;
        v[3]  = tx;      v[4]  = ty;      v[5]  = tz;
        v[6]  = px * tx; v[7]  = px * ty; v[8]  = px * tz;
        v[9]  = py * tx; v[10] = py * ty; v[11] = py * tz;
        v[12] = pz * tx; v[13] = pz * ty; v[14] = pz * tz;
        #pragma unroll
        for (int k = 0; k < 15; ++k) {
            float s = v[k];
            s += __shfl_down(s, 32);
            s += __shfl_down(s, 16);
            s += __shfl_down(s, 8);
            s += __shfl_down(s, 4);
            s += __shfl_down(s, 2);
            s += __shfl_down(s, 1);
            v[k] = s;
        }
        if (l == 0) {
            float* pp = pout + blk * 16;
            #pragma unroll
            for (int k = 0; k < 15; ++k) pp[k] = v[k];
        }
    }
}

// Final: solve iteration-10's (R,t) (redundant per block), apply, write out.
// out layout: R [4,3,3] flat (36), t [4,3] flat (12), points [4,4096,3].
__global__ __launch_bounds__(256) void icp_final(
        const float* __restrict__ S,
        const float* __restrict__ plast,
        float* __restrict__ out) {
    __shared__ float RtL[12];
    const int bk  = blockIdx.x;
    const int tid = threadIdx.x;
    const int gid = bk * 256 + tid;               // 0..16383
    const int b   = gid >> 12;

    if (tid < 64) {
        const float4* rp = (const float4*)(plast + (b * 64 + tid) * 16);
        float4 r0 = rp[0], r1 = rp[1], r2 = rp[2], r3 = rp[3];
        float sm[15] = { r0.x, r0.y, r0.z, r0.w, r1.x, r1.y, r1.z, r1.w,
                         r2.x, r2.y, r2.z, r2.w, r3.x, r3.y, r3.z };
        #pragma unroll
        for (int k = 0; k < 15; ++k) {
            float v = sm[k];
            v += __shfl_down(v, 32);
            v += __shfl_down(v, 16);
            v += __shfl_down(v, 8);
            v += __shfl_down(v, 4);
            v += __shfl_down(v, 2);
            v += __shfl_down(v, 1);
            sm[k] = v;
        }
        if (tid == 0) kabsch_f32(sm, RtL);
    }
    __syncthreads();

    float x = S[gid * 3 + 0];
    float y = S[gid * 3 + 1];
    float z = S[gid * 3 + 2];
    out[48 + gid * 3 + 0] = x * RtL[0] + y * RtL[3] + z * RtL[6] + RtL[9];
    out[48 + gid * 3 + 1] = x * RtL[1] + y * RtL[4] + z * RtL[7] + RtL[10];
    out[48 + gid * 3 + 2] = x * RtL[2] + y * RtL[5] + z * RtL[8] + RtL[11];
    if ((bk & 15) == 0) {
        if (tid < 9) out[b * 9 + tid] = RtL[tid];
        if (tid < 3) out[36 + b * 3 + tid] = RtL[9 + tid];
    }
}

extern "C" void kernel_launch(void* const* d_in, const int* in_sizes, int n_in,
                              void* d_out, int out_size, void* d_ws, size_t ws_size,
                              hipStream_t stream) {
    const float* src = (const float*)d_in[0];
    const float* tgt = (const float*)d_in[1];
    float* out = (float*)d_out;

    float* W     = (float*)d_ws;
    float4* tgt4 = (float4*)W;                       // 65536 floats
    uint4*  Bbuf = (uint4*)(W + 65536);              // 131072 floats (512 KB)
    float*  S    = W + 65536 + 131072;               // 49152 floats
    float*  pA   = S + 49152;                        // 4096 floats
    float*  pB   = pA + 4096;                        // 4096 floats
    float* bufs[2] = { pA, pB };

    icp_init<<<128, 256, 0, stream>>>(tgt, tgt4, Bbuf);
    for (int k = 0; k < 10; ++k) {
        icp_scan<<<256, 1024, 0, stream>>>(src, tgt4, Bbuf, S,
                                           bufs[(k + 1) & 1], bufs[k & 1],
                                           k == 0 ? 1 : 0);
    }
    icp_final<<<64, 256, 0, stream>>>(S, bufs[1], out);
}